// Round 1
// baseline (778.225 us; speedup 1.0000x reference)
//
#include <hip/hip_runtime.h>
#include <hip/hip_bf16.h>
#include <math.h>

#define N_ATOMS 4096
#define L_WORDS 65536
#define DD 10
#define HALO 11

// ---------------------------------------------------------------------------
// K1: fingerprint embedding gather + hs0 = relu(xs0 @ Wg0^T + bg0)
// ---------------------------------------------------------------------------
__global__ __launch_bounds__(256) void gnn_embed(
    const int* __restrict__ fp, const float* __restrict__ embed_fp,
    const float* __restrict__ Wg0, const float* __restrict__ bg0,
    float* __restrict__ xs0, float* __restrict__ hs0)
{
    int n = blockIdx.x * blockDim.x + threadIdx.x;
    if (n >= N_ATOMS) return;
    float x[DD];
    const float* e = embed_fp + (size_t)fp[n] * DD;
    #pragma unroll
    for (int d = 0; d < DD; ++d) { x[d] = e[d]; xs0[n * DD + d] = x[d]; }
    #pragma unroll
    for (int d = 0; d < DD; ++d) {
        float v = bg0[d];
        #pragma unroll
        for (int k = 0; k < DD; ++k) v += Wg0[d * DD + k] * x[k];
        hs0[n * DD + d] = fmaxf(v, 0.f);
    }
}

// ---------------------------------------------------------------------------
// K3: one GNN layer: xs_out = xs_in + A @ hs_in
//     optional epilogue: hs_out = relu(xs_out @ Wg^T + bg)  (next layer's hs)
//     optional epilogue: atomicAdd row sums into compound_acc (last layer)
// grid 512 blocks x 512 threads; 8 waves/block = 8 rows/block.
// hs staged transposed in LDS in 1024-column chunks (40 KB).
// ---------------------------------------------------------------------------
#define GNN_BLOCK 512
#define GNN_ROWS 8
#define GNN_CHUNK 1024

__global__ __launch_bounds__(GNN_BLOCK) void gnn_layer(
    const float* __restrict__ A,
    const float* __restrict__ xs_in,
    const float* __restrict__ hs_in,
    float* __restrict__ xs_out,
    float* __restrict__ hs_out,          // may be null
    const float* __restrict__ Wg,        // next-layer weights (if hs_out)
    const float* __restrict__ bg,
    float* __restrict__ compound_acc)    // may be null
{
    __shared__ float hsT[DD][GNN_CHUNK];   // 40 KB, transposed
    const int tid = threadIdx.x;
    const int wave = tid >> 6;
    const int lane = tid & 63;
    const int r = blockIdx.x * GNN_ROWS + wave;

    float acc[DD];
    #pragma unroll
    for (int d = 0; d < DD; ++d) acc[d] = 0.f;

    for (int chunk = 0; chunk < N_ATOMS / GNN_CHUNK; ++chunk) {
        const int base = chunk * GNN_CHUNK;
        for (int idx = tid; idx < GNN_CHUNK * DD; idx += GNN_BLOCK) {
            int c = idx / DD, d = idx - c * DD;
            hsT[d][c] = hs_in[(base + c) * DD + d];
        }
        __syncthreads();
        const float4* A4 = (const float4*)(A + (size_t)r * N_ATOMS + base);
        #pragma unroll
        for (int it = 0; it < GNN_CHUNK / 256; ++it) {
            float4 a = A4[it * 64 + lane];
            int cb = it * 64 + lane;
            #pragma unroll
            for (int d = 0; d < DD; ++d) {
                float4 h = ((const float4*)&hsT[d][0])[cb];
                acc[d] += a.x * h.x;
                acc[d] += a.y * h.y;
                acc[d] += a.z * h.z;
                acc[d] += a.w * h.w;
            }
        }
        __syncthreads();
    }

    // reduce acc across the 64 lanes of the wave
    #pragma unroll
    for (int off = 32; off >= 1; off >>= 1) {
        #pragma unroll
        for (int d = 0; d < DD; ++d)
            acc[d] += __shfl_down(acc[d], off, 64);
    }

    if (lane == 0) {
        float xnew[DD];
        #pragma unroll
        for (int d = 0; d < DD; ++d) {
            xnew[d] = xs_in[r * DD + d] + acc[d];
            xs_out[r * DD + d] = xnew[d];
        }
        if (hs_out) {
            #pragma unroll
            for (int d = 0; d < DD; ++d) {
                float v = bg[d];
                #pragma unroll
                for (int k = 0; k < DD; ++k) v += Wg[d * DD + k] * xnew[k];
                hs_out[r * DD + d] = fmaxf(v, 0.f);
            }
        }
        if (compound_acc) {
            #pragma unroll
            for (int d = 0; d < DD; ++d) atomicAdd(&compound_acc[d], xnew[d]);
        }
    }
}

// ---------------------------------------------------------------------------
// K6: one CNN layer over [L_WORDS, 10], 23x23 kernel, pad 11.
// Every output column uses ALL 10 input columns (|c-d|<=9 < 11), so:
//   out[l,d] = b + sum_{i=0..22} sum_{c=0..9} in[l+i-11, c] * w[i, c-d+11]
// Layer 0 fuses the word-embedding gather into the LDS staging.
// ---------------------------------------------------------------------------
#define CONV_BLOCK 256

__global__ __launch_bounds__(CONV_BLOCK) void conv_layer(
    const float* __restrict__ tin,        // null => gather from embedding
    const int* __restrict__ words,
    const float* __restrict__ embed_word,
    const float* __restrict__ w,          // [23*23]
    const float* __restrict__ bptr,       // scalar bias
    float* __restrict__ tout)
{
    __shared__ float s[(CONV_BLOCK + 2 * HALO) * 11];  // stride 11: conflict-free
    const int tid = threadIdx.x;
    const int l0 = blockIdx.x * CONV_BLOCK;

    for (int idx = tid; idx < (CONV_BLOCK + 2 * HALO) * DD; idx += CONV_BLOCK) {
        int rr = idx / DD, d = idx - rr * DD;
        int gr = l0 - HALO + rr;
        float v = 0.f;
        if (gr >= 0 && gr < L_WORDS) {
            if (tin) v = tin[(size_t)gr * DD + d];
            else     v = embed_word[(size_t)words[gr] * DD + d];
        }
        s[rr * 11 + d] = v;
    }
    __syncthreads();

    const float bias = *bptr;
    float acc[DD];
    #pragma unroll
    for (int d = 0; d < DD; ++d) acc[d] = bias;

    for (int i = 0; i < 23; ++i) {
        float row[DD];
        const float* sr = &s[(tid + i) * 11];
        #pragma unroll
        for (int c = 0; c < DD; ++c) row[c] = sr[c];
        #pragma unroll
        for (int d = 0; d < DD; ++d) {
            #pragma unroll
            for (int c = 0; c < DD; ++c)
                acc[d] += row[c] * w[i * 23 + (c - d + 11)];
        }
    }
    const int l = l0 + tid;
    #pragma unroll
    for (int d = 0; d < DD; ++d)
        tout[(size_t)l * DD + d] = fmaxf(acc[d], 0.f);
}

// ---------------------------------------------------------------------------
// K7: attention pooling.  h = relu(Wa@compound + ba) (recomputed per thread,
// uniform), per row: hp = relu(Wa@xs_p[l] + ba), wgt = tanh(h.hp),
// accumulate wgt*hp -> protein_acc (block-reduced, then atomic).
// ---------------------------------------------------------------------------
__global__ __launch_bounds__(256) void attention_pool(
    const float* __restrict__ xs_p,
    const float* __restrict__ compound_acc,   // row sums; /N_ATOMS = mean
    const float* __restrict__ Wa, const float* __restrict__ ba,
    float* __restrict__ protein_acc)
{
    const int tid = threadIdx.x;
    const int l = blockIdx.x * 256 + tid;

    float h[DD];
    #pragma unroll
    for (int d = 0; d < DD; ++d) {
        float v = ba[d];
        #pragma unroll
        for (int k = 0; k < DD; ++k)
            v += Wa[d * DD + k] * (compound_acc[k] * (1.f / N_ATOMS));
        h[d] = fmaxf(v, 0.f);
    }

    float row[DD];
    #pragma unroll
    for (int d = 0; d < DD; ++d) row[d] = xs_p[(size_t)l * DD + d];

    float hp[DD];
    float dotv = 0.f;
    #pragma unroll
    for (int d = 0; d < DD; ++d) {
        float v = ba[d];
        #pragma unroll
        for (int k = 0; k < DD; ++k) v += Wa[d * DD + k] * row[k];
        hp[d] = fmaxf(v, 0.f);
        dotv += h[d] * hp[d];
    }
    float wgt = tanhf(dotv);

    __shared__ float red[256 * DD];
    #pragma unroll
    for (int d = 0; d < DD; ++d) red[tid * DD + d] = wgt * hp[d];
    __syncthreads();
    for (int s2 = 128; s2 >= 1; s2 >>= 1) {
        if (tid < s2) {
            #pragma unroll
            for (int d = 0; d < DD; ++d)
                red[tid * DD + d] += red[(tid + s2) * DD + d];
        }
        __syncthreads();
    }
    if (tid < DD) atomicAdd(&protein_acc[tid], red[tid]);
}

// ---------------------------------------------------------------------------
// K8: fusion MLP on [1,20] -> [1,2]
// ---------------------------------------------------------------------------
__global__ __launch_bounds__(64) void final_mlp(
    const float* __restrict__ compound_acc,
    const float* __restrict__ protein_acc,
    const float* __restrict__ Wo, const float* __restrict__ bo,
    const float* __restrict__ Wi, const float* __restrict__ bi,
    float* __restrict__ out)
{
    __shared__ float cat[20];
    __shared__ float nxt[20];
    const int t = threadIdx.x;
    if (t < DD) cat[t] = compound_acc[t] * (1.f / N_ATOMS);
    else if (t < 20) cat[t] = protein_acc[t - DD] * (1.f / L_WORDS);
    __syncthreads();
    for (int j = 0; j < 3; ++j) {
        float v = 0.f;
        if (t < 20) {
            v = bo[j * 20 + t];
            for (int k = 0; k < 20; ++k) v += Wo[j * 400 + t * 20 + k] * cat[k];
        }
        __syncthreads();
        if (t < 20) cat[t] = fmaxf(v, 0.f);
        __syncthreads();
        (void)nxt;
    }
    if (t < 2) {
        float v = bi[t];
        for (int k = 0; k < 20; ++k) v += Wi[t * 20 + k] * cat[k];
        out[t] = v;
    }
}

// ---------------------------------------------------------------------------
extern "C" void kernel_launch(void* const* d_in, const int* in_sizes, int n_in,
                              void* d_out, int out_size, void* d_ws, size_t ws_size,
                              hipStream_t stream)
{
    const int*   fp     = (const int*)d_in[0];
    const float* A      = (const float*)d_in[1];
    const int*   words  = (const int*)d_in[2];
    const float* emb_fp = (const float*)d_in[3];
    const float* emb_w  = (const float*)d_in[4];
    const float* Wg     = (const float*)d_in[5];   // [3][10][10]
    const float* bg     = (const float*)d_in[6];   // [3][10]
    const float* Wc     = (const float*)d_in[7];   // [3][529]
    const float* bc     = (const float*)d_in[8];   // [3]
    const float* Wa     = (const float*)d_in[9];   // [10][10]
    const float* ba     = (const float*)d_in[10];  // [10]
    const float* Wo     = (const float*)d_in[11];  // [3][20][20]
    const float* bo     = (const float*)d_in[12];  // [3][20]
    const float* Wi     = (const float*)d_in[13];  // [2][20]
    const float* bi     = (const float*)d_in[14];  // [2]
    float* out = (float*)d_out;
    float* ws  = (float*)d_ws;

    float* xs0 = ws;                       // 40960
    float* xs1 = ws + 40960;               // 40960
    float* hs0 = ws + 81920;               // 40960
    float* hs1 = ws + 122880;              // 40960
    float* t0  = ws + 163840;              // 655360
    float* t1  = ws + 163840 + 655360;     // 655360
    float* comp_acc = ws + 163840 + 2 * 655360;  // 10 (+pad)
    float* prot_acc = comp_acc + 16;             // 10

    hipMemsetAsync(comp_acc, 0, 32 * sizeof(float), stream);

    // ---- GNN ----
    gnn_embed<<<N_ATOMS / 256, 256, 0, stream>>>(fp, emb_fp, Wg, bg, xs0, hs0);
    gnn_layer<<<N_ATOMS / GNN_ROWS, GNN_BLOCK, 0, stream>>>(
        A, xs0, hs0, xs1, hs1, Wg + 100, bg + 10, nullptr);
    gnn_layer<<<N_ATOMS / GNN_ROWS, GNN_BLOCK, 0, stream>>>(
        A, xs1, hs1, xs0, hs0, Wg + 200, bg + 20, nullptr);
    gnn_layer<<<N_ATOMS / GNN_ROWS, GNN_BLOCK, 0, stream>>>(
        A, xs0, hs0, xs1, nullptr, nullptr, nullptr, comp_acc);

    // ---- CNN ---- (layer0 fuses embedding gather)
    conv_layer<<<L_WORDS / CONV_BLOCK, CONV_BLOCK, 0, stream>>>(
        nullptr, words, emb_w, Wc, bc, t0);
    conv_layer<<<L_WORDS / CONV_BLOCK, CONV_BLOCK, 0, stream>>>(
        t0, nullptr, nullptr, Wc + 529, bc + 1, t1);
    conv_layer<<<L_WORDS / CONV_BLOCK, CONV_BLOCK, 0, stream>>>(
        t1, nullptr, nullptr, Wc + 1058, bc + 2, t0);

    // ---- attention + fusion ----
    attention_pool<<<L_WORDS / 256, 256, 0, stream>>>(t0, comp_acc, Wa, ba, prot_acc);
    final_mlp<<<1, 64, 0, stream>>>(comp_acc, prot_acc, Wo, bo, Wi, bi, out);
}

// Round 2
// 283.180 us; speedup vs baseline: 2.7482x; 2.7482x over previous
//
#include <hip/hip_runtime.h>
#include <hip/hip_bf16.h>
#include <math.h>

#define N_ATOMS 4096
#define L_WORDS 65536
#define DD 10
#define HALO 11

// ---------------------------------------------------------------------------
// K1: fingerprint embedding gather; xs0 row-major, hs0 TRANSPOSED [d][n]
// ---------------------------------------------------------------------------
__global__ __launch_bounds__(256) void gnn_embed(
    const int* __restrict__ fp, const float* __restrict__ embed_fp,
    const float* __restrict__ Wg0, const float* __restrict__ bg0,
    float* __restrict__ xs0, float* __restrict__ hsT0)
{
    int n = blockIdx.x * blockDim.x + threadIdx.x;
    if (n >= N_ATOMS) return;
    float x[DD];
    const float* e = embed_fp + (size_t)fp[n] * DD;
    #pragma unroll
    for (int d = 0; d < DD; ++d) { x[d] = e[d]; xs0[n * DD + d] = x[d]; }
    #pragma unroll
    for (int d = 0; d < DD; ++d) {
        float v = bg0[d];
        #pragma unroll
        for (int k = 0; k < DD; ++k) v += Wg0[d * DD + k] * x[k];
        hsT0[d * N_ATOMS + n] = fmaxf(v, 0.f);   // coalesced per d
    }
}

// ---------------------------------------------------------------------------
// K2: GNN layer: xs_out = xs_in + A @ hs, hs given TRANSPOSED hsT_in[10][4096].
// One wave per row, 8 waves/block, NO LDS / NO barriers in the hot loop.
// Each lane: 16 float4 of A + 160 float4 of hsT (L2-hot), all coalesced.
// Epilogue (lane 0): xs_out, next layer's hsT_out (transposed), or per-block
// compound partial sums (last layer).
// ---------------------------------------------------------------------------
#define GNN_BLOCK 512
#define GNN_WAVES 8

__global__ __launch_bounds__(GNN_BLOCK) void gnn_layer(
    const float* __restrict__ A,
    const float* __restrict__ xs_in,
    const float* __restrict__ hsT_in,
    float* __restrict__ xs_out,
    float* __restrict__ hsT_out,         // may be null
    const float* __restrict__ Wg,        // next-layer weights (if hsT_out)
    const float* __restrict__ bg,
    float* __restrict__ comp_part)       // may be null; [gridDim.x][DD]
{
    const int tid = threadIdx.x;
    const int wave = tid >> 6;
    const int lane = tid & 63;
    const int r = blockIdx.x * GNN_WAVES + wave;

    float acc[DD];
    #pragma unroll
    for (int d = 0; d < DD; ++d) acc[d] = 0.f;

    const float4* A4 = (const float4*)(A + (size_t)r * N_ATOMS);
    #pragma unroll 4
    for (int it = 0; it < N_ATOMS / 256; ++it) {
        const int cb = it * 64 + lane;
        float4 a = A4[cb];
        #pragma unroll
        for (int d = 0; d < DD; ++d) {
            float4 h = ((const float4*)(hsT_in + (size_t)d * N_ATOMS))[cb];
            acc[d] += a.x * h.x;
            acc[d] += a.y * h.y;
            acc[d] += a.z * h.z;
            acc[d] += a.w * h.w;
        }
    }

    #pragma unroll
    for (int off = 32; off >= 1; off >>= 1) {
        #pragma unroll
        for (int d = 0; d < DD; ++d)
            acc[d] += __shfl_down(acc[d], off, 64);
    }

    __shared__ float cs[GNN_WAVES][DD];

    if (lane == 0) {
        float xnew[DD];
        #pragma unroll
        for (int d = 0; d < DD; ++d) {
            xnew[d] = xs_in[r * DD + d] + acc[d];
            xs_out[r * DD + d] = xnew[d];
        }
        if (hsT_out) {
            #pragma unroll
            for (int d = 0; d < DD; ++d) {
                float v = bg[d];
                #pragma unroll
                for (int k = 0; k < DD; ++k) v += Wg[d * DD + k] * xnew[k];
                hsT_out[(size_t)d * N_ATOMS + r] = fmaxf(v, 0.f);
            }
        }
        if (comp_part) {
            #pragma unroll
            for (int d = 0; d < DD; ++d) cs[wave][d] = xnew[d];
        }
    }
    if (comp_part) {
        __syncthreads();
        if (tid < DD) {
            float s = 0.f;
            #pragma unroll
            for (int w = 0; w < GNN_WAVES; ++w) s += cs[w][tid];
            comp_part[blockIdx.x * DD + tid] = s;
        }
    }
}

// ---------------------------------------------------------------------------
// K3: reduce compound partials [512][10] -> comp[10] (mean over rows)
// ---------------------------------------------------------------------------
__global__ __launch_bounds__(256) void reduce_comp(
    const float* __restrict__ part, int npart, float* __restrict__ comp)
{
    const int tid = threadIdx.x, wave = tid >> 6, lane = tid & 63;
    float v[DD];
    #pragma unroll
    for (int d = 0; d < DD; ++d) v[d] = 0.f;
    for (int p = tid; p < npart; p += 256) {
        #pragma unroll
        for (int d = 0; d < DD; ++d) v[d] += part[p * DD + d];
    }
    #pragma unroll
    for (int off = 32; off >= 1; off >>= 1) {
        #pragma unroll
        for (int d = 0; d < DD; ++d) v[d] += __shfl_down(v[d], off, 64);
    }
    __shared__ float s[4][DD];
    if (lane == 0) {
        #pragma unroll
        for (int d = 0; d < DD; ++d) s[wave][d] = v[d];
    }
    __syncthreads();
    if (tid < DD)
        comp[tid] = (s[0][tid] + s[1][tid] + s[2][tid] + s[3][tid]) * (1.f / N_ATOMS);
}

// ---------------------------------------------------------------------------
// K4: one CNN layer over [L_WORDS, 10], 23x23 kernel, pad 11.
//   out[l,d] = relu(b + sum_i sum_c in[l+i-11, c] * w[i, c-d+11])
// Layer 0 fuses the word-embedding gather into the LDS staging.
// ---------------------------------------------------------------------------
#define CONV_BLOCK 256

__global__ __launch_bounds__(CONV_BLOCK) void conv_layer(
    const float* __restrict__ tin,        // null => gather from embedding
    const int* __restrict__ words,
    const float* __restrict__ embed_word,
    const float* __restrict__ w,          // [23*23]
    const float* __restrict__ bptr,       // scalar bias
    float* __restrict__ tout)
{
    __shared__ float s[(CONV_BLOCK + 2 * HALO) * 11];  // stride 11: conflict-free
    const int tid = threadIdx.x;
    const int l0 = blockIdx.x * CONV_BLOCK;

    for (int idx = tid; idx < (CONV_BLOCK + 2 * HALO) * DD; idx += CONV_BLOCK) {
        int rr = idx / DD, d = idx - rr * DD;
        int gr = l0 - HALO + rr;
        float v = 0.f;
        if (gr >= 0 && gr < L_WORDS) {
            if (tin) v = tin[(size_t)gr * DD + d];
            else     v = embed_word[(size_t)words[gr] * DD + d];
        }
        s[rr * 11 + d] = v;
    }
    __syncthreads();

    const float bias = *bptr;
    float acc[DD];
    #pragma unroll
    for (int d = 0; d < DD; ++d) acc[d] = bias;

    for (int i = 0; i < 23; ++i) {
        float row[DD];
        const float* sr = &s[(tid + i) * 11];
        #pragma unroll
        for (int c = 0; c < DD; ++c) row[c] = sr[c];
        #pragma unroll
        for (int d = 0; d < DD; ++d) {
            #pragma unroll
            for (int c = 0; c < DD; ++c)
                acc[d] += row[c] * w[i * 23 + (c - d + 11)];
        }
    }
    const int l = l0 + tid;
    #pragma unroll
    for (int d = 0; d < DD; ++d)
        tout[(size_t)l * DD + d] = fmaxf(acc[d], 0.f);
}

// ---------------------------------------------------------------------------
// K5: attention pooling -> per-block partial sums of wgt*hp  [64][10]
// ---------------------------------------------------------------------------
__global__ __launch_bounds__(1024) void attention_pool(
    const float* __restrict__ xs_p,
    const float* __restrict__ comp,            // [10], already meaned
    const float* __restrict__ Wa, const float* __restrict__ ba,
    float* __restrict__ att_part)              // [gridDim.x][DD]
{
    const int tid = threadIdx.x, wave = tid >> 6, lane = tid & 63;
    const int l = blockIdx.x * 1024 + tid;

    float h[DD];
    #pragma unroll
    for (int d = 0; d < DD; ++d) {
        float v = ba[d];
        #pragma unroll
        for (int k = 0; k < DD; ++k) v += Wa[d * DD + k] * comp[k];
        h[d] = fmaxf(v, 0.f);
    }

    float row[DD];
    #pragma unroll
    for (int d = 0; d < DD; ++d) row[d] = xs_p[(size_t)l * DD + d];

    float hp[DD], dotv = 0.f;
    #pragma unroll
    for (int d = 0; d < DD; ++d) {
        float v = ba[d];
        #pragma unroll
        for (int k = 0; k < DD; ++k) v += Wa[d * DD + k] * row[k];
        hp[d] = fmaxf(v, 0.f);
        dotv += h[d] * hp[d];
    }
    const float wgt = tanhf(dotv);

    float y[DD];
    #pragma unroll
    for (int d = 0; d < DD; ++d) y[d] = wgt * hp[d];

    #pragma unroll
    for (int off = 32; off >= 1; off >>= 1) {
        #pragma unroll
        for (int d = 0; d < DD; ++d) y[d] += __shfl_down(y[d], off, 64);
    }
    __shared__ float s[16][DD];
    if (lane == 0) {
        #pragma unroll
        for (int d = 0; d < DD; ++d) s[wave][d] = y[d];
    }
    __syncthreads();
    if (tid < DD) {
        float v = 0.f;
        #pragma unroll
        for (int wv = 0; wv < 16; ++wv) v += s[wv][tid];
        att_part[blockIdx.x * DD + tid] = v;
    }
}

// ---------------------------------------------------------------------------
// K6: reduce att partials [64][10] -> protein mean; fusion MLP -> out[2]
// ---------------------------------------------------------------------------
__global__ __launch_bounds__(64) void final_mlp(
    const float* __restrict__ comp,            // [10] meaned
    const float* __restrict__ att_part,        // [64][10]
    const float* __restrict__ Wo, const float* __restrict__ bo,
    const float* __restrict__ Wi, const float* __restrict__ bi,
    float* __restrict__ out)
{
    const int t = threadIdx.x;
    float a[DD];
    #pragma unroll
    for (int d = 0; d < DD; ++d) a[d] = att_part[t * DD + d];
    #pragma unroll
    for (int off = 32; off >= 1; off >>= 1) {
        #pragma unroll
        for (int d = 0; d < DD; ++d) a[d] += __shfl_down(a[d], off, 64);
    }

    __shared__ float cat[20];
    if (t < DD) cat[t] = comp[t];
    if (t == 0) {
        #pragma unroll
        for (int d = 0; d < DD; ++d) cat[DD + d] = a[d] * (1.f / L_WORDS);
    }
    __syncthreads();

    for (int j = 0; j < 3; ++j) {
        float v = 0.f;
        if (t < 20) {
            v = bo[j * 20 + t];
            for (int k = 0; k < 20; ++k) v += Wo[j * 400 + t * 20 + k] * cat[k];
        }
        __syncthreads();
        if (t < 20) cat[t] = fmaxf(v, 0.f);
        __syncthreads();
    }
    if (t < 2) {
        float v = bi[t];
        for (int k = 0; k < 20; ++k) v += Wi[t * 20 + k] * cat[k];
        out[t] = v;
    }
}

// ---------------------------------------------------------------------------
extern "C" void kernel_launch(void* const* d_in, const int* in_sizes, int n_in,
                              void* d_out, int out_size, void* d_ws, size_t ws_size,
                              hipStream_t stream)
{
    const int*   fp     = (const int*)d_in[0];
    const float* A      = (const float*)d_in[1];
    const int*   words  = (const int*)d_in[2];
    const float* emb_fp = (const float*)d_in[3];
    const float* emb_w  = (const float*)d_in[4];
    const float* Wg     = (const float*)d_in[5];   // [3][10][10]
    const float* bg     = (const float*)d_in[6];   // [3][10]
    const float* Wc     = (const float*)d_in[7];   // [3][529]
    const float* bc     = (const float*)d_in[8];   // [3]
    const float* Wa     = (const float*)d_in[9];   // [10][10]
    const float* ba     = (const float*)d_in[10];  // [10]
    const float* Wo     = (const float*)d_in[11];  // [3][20][20]
    const float* bo     = (const float*)d_in[12];  // [3][20]
    const float* Wi     = (const float*)d_in[13];  // [2][20]
    const float* bi     = (const float*)d_in[14];  // [2]
    float* out = (float*)d_out;
    float* ws  = (float*)d_ws;

    float* xs0  = ws;                        // 40960
    float* xs1  = ws + 40960;                // 40960
    float* hsT0 = ws + 81920;                // 40960 (10 x 4096)
    float* hsT1 = ws + 122880;               // 40960
    float* t0   = ws + 163840;               // 655360
    float* t1   = ws + 163840 + 655360;      // 655360
    float* comp = ws + 163840 + 2 * 655360;  // 16
    // reuse dead regions for partials (no extra ws growth):
    float* comp_part = hsT1;   // [512][10]; hsT1 not read by last layer
    float* att_part  = hsT0;   // [64][10];  written after GNN fully done

    const int gnn_grid = N_ATOMS / GNN_WAVES;   // 512

    // ---- GNN ----
    gnn_embed<<<N_ATOMS / 256, 256, 0, stream>>>(fp, emb_fp, Wg, bg, xs0, hsT0);
    gnn_layer<<<gnn_grid, GNN_BLOCK, 0, stream>>>(
        A, xs0, hsT0, xs1, hsT1, Wg + 100, bg + 10, nullptr);
    gnn_layer<<<gnn_grid, GNN_BLOCK, 0, stream>>>(
        A, xs1, hsT1, xs0, hsT0, Wg + 200, bg + 20, nullptr);
    gnn_layer<<<gnn_grid, GNN_BLOCK, 0, stream>>>(
        A, xs0, hsT0, xs1, nullptr, nullptr, nullptr, comp_part);
    reduce_comp<<<1, 256, 0, stream>>>(comp_part, gnn_grid, comp);

    // ---- CNN ---- (layer0 fuses embedding gather)
    conv_layer<<<L_WORDS / CONV_BLOCK, CONV_BLOCK, 0, stream>>>(
        nullptr, words, emb_w, Wc, bc, t0);
    conv_layer<<<L_WORDS / CONV_BLOCK, CONV_BLOCK, 0, stream>>>(
        t0, nullptr, nullptr, Wc + 529, bc + 1, t1);
    conv_layer<<<L_WORDS / CONV_BLOCK, CONV_BLOCK, 0, stream>>>(
        t1, nullptr, nullptr, Wc + 1058, bc + 2, t0);

    // ---- attention + fusion ----
    attention_pool<<<L_WORDS / 1024, 1024, 0, stream>>>(t0, comp, Wa, ba, att_part);
    final_mlp<<<1, 64, 0, stream>>>(comp, att_part, Wo, bo, Wi, bi, out);
}

// Round 3
// 274.636 us; speedup vs baseline: 2.8337x; 1.0311x over previous
//
#include <hip/hip_runtime.h>
#include <hip/hip_bf16.h>
#include <math.h>

#define N_ATOMS 4096
#define L_WORDS 65536
#define DD 10
#define HALO 11

// ---------------------------------------------------------------------------
// K1: fingerprint embedding gather; xs0 row-major, hs0 TRANSPOSED [d][n]
// ---------------------------------------------------------------------------
__global__ __launch_bounds__(256) void gnn_embed(
    const int* __restrict__ fp, const float* __restrict__ embed_fp,
    const float* __restrict__ Wg0, const float* __restrict__ bg0,
    float* __restrict__ xs0, float* __restrict__ hsT0)
{
    int n = blockIdx.x * blockDim.x + threadIdx.x;
    if (n >= N_ATOMS) return;
    float x[DD];
    const float* e = embed_fp + (size_t)fp[n] * DD;
    #pragma unroll
    for (int d = 0; d < DD; ++d) { x[d] = e[d]; xs0[n * DD + d] = x[d]; }
    #pragma unroll
    for (int d = 0; d < DD; ++d) {
        float v = bg0[d];
        #pragma unroll
        for (int k = 0; k < DD; ++k) v += Wg0[d * DD + k] * x[k];
        hsT0[d * N_ATOMS + n] = fmaxf(v, 0.f);   // coalesced per d
    }
}

// ---------------------------------------------------------------------------
// K2: GNN layer: xs_out = xs_in + A @ hs   (hsT_in transposed [10][4096])
// Block = 512 = 8 waves. Waves 0..3: row-groups 0..3 (4 rows each), cols
// 0..2047. Waves 4..7: same row-groups, cols 2048..4095. 16 rows/block,
// grid 256 -> 2048 waves (2/SIMD). Each wave reads only half of hsT:
// L2 traffic 164 MB/layer vs 655 MB with 1 row/wave.
// Per iter: 14 independent float4 loads feed 160 FMAs.
// ---------------------------------------------------------------------------
#define GNN_BLOCK 512
#define GNN_RPW 4                 // rows per wave
#define GNN_ROWS_BLK 16           // rows per block
#define HALFC (N_ATOMS / 2)       // 2048 columns per wave

__global__ __launch_bounds__(GNN_BLOCK, 2) void gnn_layer(
    const float* __restrict__ A,
    const float* __restrict__ xs_in,
    const float* __restrict__ hsT_in,
    float* __restrict__ xs_out,
    float* __restrict__ hsT_out,         // may be null
    const float* __restrict__ Wg,        // next-layer weights (if hsT_out)
    const float* __restrict__ bg,
    float* __restrict__ comp_part)       // may be null; [gridDim.x][DD]
{
    const int tid  = threadIdx.x;
    const int wave = tid >> 6;
    const int lane = tid & 63;
    const int rg   = wave & 3;           // row group 0..3
    const int ch   = wave >> 2;          // column half 0/1
    const int rowblk = blockIdx.x * GNN_ROWS_BLK;
    const int r0   = rowblk + rg * GNN_RPW;
    const int cbase = ch * HALFC;        // float offset of this wave's cols

    float acc[GNN_RPW][DD];
    #pragma unroll
    for (int r = 0; r < GNN_RPW; ++r)
        #pragma unroll
        for (int d = 0; d < DD; ++d) acc[r][d] = 0.f;

    const float4* Arow[GNN_RPW];
    #pragma unroll
    for (int r = 0; r < GNN_RPW; ++r)
        Arow[r] = (const float4*)(A + (size_t)(r0 + r) * N_ATOMS + cbase);
    const float4* H4 = (const float4*)(hsT_in + cbase);
    const int stride4 = N_ATOMS / 4;     // float4 stride between hsT rows

    // 2048 cols = 512 float4 / 64 lanes = 8 iterations
    #pragma unroll 2
    for (int it = 0; it < HALFC / 256; ++it) {
        const int cb = it * 64 + lane;
        float4 a[GNN_RPW];
        #pragma unroll
        for (int r = 0; r < GNN_RPW; ++r) a[r] = Arow[r][cb];
        #pragma unroll
        for (int d = 0; d < DD; ++d) {
            float4 h = H4[d * stride4 + cb];
            #pragma unroll
            for (int r = 0; r < GNN_RPW; ++r) {
                acc[r][d] += a[r].x * h.x;
                acc[r][d] += a[r].y * h.y;
                acc[r][d] += a[r].z * h.z;
                acc[r][d] += a[r].w * h.w;
            }
        }
    }

    // wave-level reduce of 40 partials
    #pragma unroll
    for (int off = 32; off >= 1; off >>= 1) {
        #pragma unroll
        for (int r = 0; r < GNN_RPW; ++r)
            #pragma unroll
            for (int d = 0; d < DD; ++d)
                acc[r][d] += __shfl_down(acc[r][d], off, 64);
    }

    __shared__ float part[8][GNN_RPW][DD];   // per-wave partials
    __shared__ float xnew[GNN_ROWS_BLK][DD];
    if (lane == 0) {
        #pragma unroll
        for (int r = 0; r < GNN_RPW; ++r)
            #pragma unroll
            for (int d = 0; d < DD; ++d) part[wave][r][d] = acc[r][d];
    }
    __syncthreads();

    // combine column halves, add xs_in, write xs_out
    if (tid < GNN_ROWS_BLK * DD) {
        const int row = tid / DD, d = tid - row * DD;
        const int g = row >> 2, ri = row & 3;    // row group / idx in group
        float v = part[g][ri][d] + part[g + 4][ri][d]
                + xs_in[(rowblk + row) * DD + d];
        xs_out[(rowblk + row) * DD + d] = v;
        xnew[row][d] = v;
    }
    __syncthreads();

    if (hsT_out) {
        if (tid < GNN_ROWS_BLK * DD) {
            const int row = tid / DD, d = tid - row * DD;
            float v = bg[d];
            #pragma unroll
            for (int k = 0; k < DD; ++k) v += Wg[d * DD + k] * xnew[row][k];
            hsT_out[(size_t)d * N_ATOMS + rowblk + row] = fmaxf(v, 0.f);
        }
    }
    if (comp_part) {
        if (tid < DD) {
            float s = 0.f;
            #pragma unroll
            for (int row = 0; row < GNN_ROWS_BLK; ++row) s += xnew[row][tid];
            comp_part[blockIdx.x * DD + tid] = s;
        }
    }
}

// ---------------------------------------------------------------------------
// K3: reduce compound partials [256][10] -> comp[10] (mean over rows)
// ---------------------------------------------------------------------------
__global__ __launch_bounds__(256) void reduce_comp(
    const float* __restrict__ part, int npart, float* __restrict__ comp)
{
    const int tid = threadIdx.x, wave = tid >> 6, lane = tid & 63;
    float v[DD];
    #pragma unroll
    for (int d = 0; d < DD; ++d) v[d] = 0.f;
    for (int p = tid; p < npart; p += 256) {
        #pragma unroll
        for (int d = 0; d < DD; ++d) v[d] += part[p * DD + d];
    }
    #pragma unroll
    for (int off = 32; off >= 1; off >>= 1) {
        #pragma unroll
        for (int d = 0; d < DD; ++d) v[d] += __shfl_down(v[d], off, 64);
    }
    __shared__ float s[4][DD];
    if (lane == 0) {
        #pragma unroll
        for (int d = 0; d < DD; ++d) s[wave][d] = v[d];
    }
    __syncthreads();
    if (tid < DD)
        comp[tid] = (s[0][tid] + s[1][tid] + s[2][tid] + s[3][tid]) * (1.f / N_ATOMS);
}

// ---------------------------------------------------------------------------
// K4: one CNN layer over [L_WORDS, 10], 23x23 kernel, pad 11.
//   out[l,d] = relu(b + sum_i sum_c in[l+i-11, c] * w[i, c-d+11])
// Layer 0 fuses the word-embedding gather into the LDS staging.
// LDS stride 11 (odd): lanes stride-11 words -> 2 lanes/bank = free.
// ---------------------------------------------------------------------------
#define CONV_BLOCK 256

__global__ __launch_bounds__(CONV_BLOCK) void conv_layer(
    const float* __restrict__ tin,        // null => gather from embedding
    const int* __restrict__ words,
    const float* __restrict__ embed_word,
    const float* __restrict__ w,          // [23*23]
    const float* __restrict__ bptr,       // scalar bias
    float* __restrict__ tout)
{
    __shared__ float s[(CONV_BLOCK + 2 * HALO) * 11];
    const int tid = threadIdx.x;
    const int l0 = blockIdx.x * CONV_BLOCK;

    for (int idx = tid; idx < (CONV_BLOCK + 2 * HALO) * DD; idx += CONV_BLOCK) {
        int rr = idx / DD, d = idx - rr * DD;
        int gr = l0 - HALO + rr;
        float v = 0.f;
        if (gr >= 0 && gr < L_WORDS) {
            if (tin) v = tin[(size_t)gr * DD + d];
            else     v = embed_word[(size_t)words[gr] * DD + d];
        }
        s[rr * 11 + d] = v;
    }
    __syncthreads();

    const float bias = *bptr;
    float acc[DD];
    #pragma unroll
    for (int d = 0; d < DD; ++d) acc[d] = bias;

    for (int i = 0; i < 23; ++i) {
        float row[DD];
        const float* sr = &s[(tid + i) * 11];
        #pragma unroll
        for (int c = 0; c < DD; ++c) row[c] = sr[c];
        #pragma unroll
        for (int d = 0; d < DD; ++d) {
            #pragma unroll
            for (int c = 0; c < DD; ++c)
                acc[d] += row[c] * w[i * 23 + (c - d + 11)];
        }
    }
    const int l = l0 + tid;
    #pragma unroll
    for (int d = 0; d < DD; ++d)
        tout[(size_t)l * DD + d] = fmaxf(acc[d], 0.f);
}

// ---------------------------------------------------------------------------
// K5: attention pooling -> per-block partial sums of wgt*hp  [64][10]
// ---------------------------------------------------------------------------
__global__ __launch_bounds__(1024) void attention_pool(
    const float* __restrict__ xs_p,
    const float* __restrict__ comp,            // [10], already meaned
    const float* __restrict__ Wa, const float* __restrict__ ba,
    float* __restrict__ att_part)              // [gridDim.x][DD]
{
    const int tid = threadIdx.x, wave = tid >> 6, lane = tid & 63;
    const int l = blockIdx.x * 1024 + tid;

    float h[DD];
    #pragma unroll
    for (int d = 0; d < DD; ++d) {
        float v = ba[d];
        #pragma unroll
        for (int k = 0; k < DD; ++k) v += Wa[d * DD + k] * comp[k];
        h[d] = fmaxf(v, 0.f);
    }

    float row[DD];
    #pragma unroll
    for (int d = 0; d < DD; ++d) row[d] = xs_p[(size_t)l * DD + d];

    float hp[DD], dotv = 0.f;
    #pragma unroll
    for (int d = 0; d < DD; ++d) {
        float v = ba[d];
        #pragma unroll
        for (int k = 0; k < DD; ++k) v += Wa[d * DD + k] * row[k];
        hp[d] = fmaxf(v, 0.f);
        dotv += h[d] * hp[d];
    }
    const float wgt = tanhf(dotv);

    float y[DD];
    #pragma unroll
    for (int d = 0; d < DD; ++d) y[d] = wgt * hp[d];

    #pragma unroll
    for (int off = 32; off >= 1; off >>= 1) {
        #pragma unroll
        for (int d = 0; d < DD; ++d) y[d] += __shfl_down(y[d], off, 64);
    }
    __shared__ float s[16][DD];
    if (lane == 0) {
        #pragma unroll
        for (int d = 0; d < DD; ++d) s[wave][d] = y[d];
    }
    __syncthreads();
    if (tid < DD) {
        float v = 0.f;
        #pragma unroll
        for (int wv = 0; wv < 16; ++wv) v += s[wv][tid];
        att_part[blockIdx.x * DD + tid] = v;
    }
}

// ---------------------------------------------------------------------------
// K6: reduce att partials [64][10] -> protein mean; fusion MLP -> out[2]
// ---------------------------------------------------------------------------
__global__ __launch_bounds__(64) void final_mlp(
    const float* __restrict__ comp,            // [10] meaned
    const float* __restrict__ att_part,        // [64][10]
    const float* __restrict__ Wo, const float* __restrict__ bo,
    const float* __restrict__ Wi, const float* __restrict__ bi,
    float* __restrict__ out)
{
    const int t = threadIdx.x;
    float a[DD];
    #pragma unroll
    for (int d = 0; d < DD; ++d) a[d] = att_part[t * DD + d];
    #pragma unroll
    for (int off = 32; off >= 1; off >>= 1) {
        #pragma unroll
        for (int d = 0; d < DD; ++d) a[d] += __shfl_down(a[d], off, 64);
    }

    __shared__ float cat[20];
    if (t < DD) cat[t] = comp[t];
    if (t == 0) {
        #pragma unroll
        for (int d = 0; d < DD; ++d) cat[DD + d] = a[d] * (1.f / L_WORDS);
    }
    __syncthreads();

    for (int j = 0; j < 3; ++j) {
        float v = 0.f;
        if (t < 20) {
            v = bo[j * 20 + t];
            for (int k = 0; k < 20; ++k) v += Wo[j * 400 + t * 20 + k] * cat[k];
        }
        __syncthreads();
        if (t < 20) cat[t] = fmaxf(v, 0.f);
        __syncthreads();
    }
    if (t < 2) {
        float v = bi[t];
        for (int k = 0; k < 20; ++k) v += Wi[t * 20 + k] * cat[k];
        out[t] = v;
    }
}

// ---------------------------------------------------------------------------
extern "C" void kernel_launch(void* const* d_in, const int* in_sizes, int n_in,
                              void* d_out, int out_size, void* d_ws, size_t ws_size,
                              hipStream_t stream)
{
    const int*   fp     = (const int*)d_in[0];
    const float* A      = (const float*)d_in[1];
    const int*   words  = (const int*)d_in[2];
    const float* emb_fp = (const float*)d_in[3];
    const float* emb_w  = (const float*)d_in[4];
    const float* Wg     = (const float*)d_in[5];   // [3][10][10]
    const float* bg     = (const float*)d_in[6];   // [3][10]
    const float* Wc     = (const float*)d_in[7];   // [3][529]
    const float* bc     = (const float*)d_in[8];   // [3]
    const float* Wa     = (const float*)d_in[9];   // [10][10]
    const float* ba     = (const float*)d_in[10];  // [10]
    const float* Wo     = (const float*)d_in[11];  // [3][20][20]
    const float* bo     = (const float*)d_in[12];  // [3][20]
    const float* Wi     = (const float*)d_in[13];  // [2][20]
    const float* bi     = (const float*)d_in[14];  // [2]
    float* out = (float*)d_out;
    float* ws  = (float*)d_ws;

    float* xs0  = ws;                        // 40960
    float* xs1  = ws + 40960;                // 40960
    float* hsT0 = ws + 81920;                // 40960 (10 x 4096)
    float* hsT1 = ws + 122880;               // 40960
    float* t0   = ws + 163840;               // 655360
    float* t1   = ws + 163840 + 655360;      // 655360
    float* comp = ws + 163840 + 2 * 655360;  // 16
    // reuse dead regions for partials:
    float* comp_part = hsT1;   // [256][10]; hsT1 not read by last layer
    float* att_part  = hsT0;   // [64][10];  written after GNN fully done

    const int gnn_grid = N_ATOMS / GNN_ROWS_BLK;   // 256

    // ---- GNN ----
    gnn_embed<<<N_ATOMS / 256, 256, 0, stream>>>(fp, emb_fp, Wg, bg, xs0, hsT0);
    gnn_layer<<<gnn_grid, GNN_BLOCK, 0, stream>>>(
        A, xs0, hsT0, xs1, hsT1, Wg + 100, bg + 10, nullptr);
    gnn_layer<<<gnn_grid, GNN_BLOCK, 0, stream>>>(
        A, xs1, hsT1, xs0, hsT0, Wg + 200, bg + 20, nullptr);
    gnn_layer<<<gnn_grid, GNN_BLOCK, 0, stream>>>(
        A, xs0, hsT0, xs1, nullptr, nullptr, nullptr, comp_part);
    reduce_comp<<<1, 256, 0, stream>>>(comp_part, gnn_grid, comp);

    // ---- CNN ---- (layer0 fuses embedding gather)
    conv_layer<<<L_WORDS / CONV_BLOCK, CONV_BLOCK, 0, stream>>>(
        nullptr, words, emb_w, Wc, bc, t0);
    conv_layer<<<L_WORDS / CONV_BLOCK, CONV_BLOCK, 0, stream>>>(
        t0, nullptr, nullptr, Wc + 529, bc + 1, t1);
    conv_layer<<<L_WORDS / CONV_BLOCK, CONV_BLOCK, 0, stream>>>(
        t1, nullptr, nullptr, Wc + 1058, bc + 2, t0);

    // ---- attention + fusion ----
    attention_pool<<<L_WORDS / 1024, 1024, 0, stream>>>(t0, comp, Wa, ba, att_part);
    final_mlp<<<1, 64, 0, stream>>>(comp, att_part, Wo, bo, Wi, bi, out);
}

// Round 4
// 263.238 us; speedup vs baseline: 2.9564x; 1.0433x over previous
//
#include <hip/hip_runtime.h>
#include <hip/hip_bf16.h>
#include <math.h>

#define N_ATOMS 4096
#define L_WORDS 65536
#define DD 10
#define HALO 11

// ---------------------------------------------------------------------------
// K1: fingerprint embedding gather; xs0 row-major, hs0 TRANSPOSED [d][n]
// ---------------------------------------------------------------------------
__global__ __launch_bounds__(256) void gnn_embed(
    const int* __restrict__ fp, const float* __restrict__ embed_fp,
    const float* __restrict__ Wg0, const float* __restrict__ bg0,
    float* __restrict__ xs0, float* __restrict__ hsT0)
{
    int n = blockIdx.x * blockDim.x + threadIdx.x;
    if (n >= N_ATOMS) return;
    float x[DD];
    const float* e = embed_fp + (size_t)fp[n] * DD;
    #pragma unroll
    for (int d = 0; d < DD; ++d) { x[d] = e[d]; xs0[n * DD + d] = x[d]; }
    #pragma unroll
    for (int d = 0; d < DD; ++d) {
        float v = bg0[d];
        #pragma unroll
        for (int k = 0; k < DD; ++k) v += Wg0[d * DD + k] * x[k];
        hsT0[d * N_ATOMS + n] = fmaxf(v, 0.f);   // coalesced per d
    }
}

// ---------------------------------------------------------------------------
// K2a: gnn_partial — partial dot-products of A @ hs over a column QUARTER.
// Block = 256 thr (4 waves), rows/block = 16 (4 rows/wave), cols = 1024.
// grid = 256 row-groups x 4 quarters = 1024 blocks (4 blocks/CU, 4 w/SIMD).
// hsT quarter (40 KB) staged in LDS once -> hot loop's vmem queue carries
// ONLY the A stream (16 dwordx4 in flight per wave, fully unrolled);
// h comes from ds_read_b128 (separate lgkmcnt queue, conflict-free).
// part[q][n][d] written per wave by lane 0.
// ---------------------------------------------------------------------------
#define GP_BLOCK 256
#define GP_RPW 4
#define GP_ROWS_BLK 16
#define GP_QCOLS 1024

__global__ __launch_bounds__(GP_BLOCK, 3) void gnn_partial(
    const float* __restrict__ A,
    const float* __restrict__ hsT_in,
    float* __restrict__ part)            // [4][N_ATOMS][DD]
{
    __shared__ float sh[DD * GP_QCOLS];  // 40 KB
    const int tid = threadIdx.x, wave = tid >> 6, lane = tid & 63;
    const int q = blockIdx.x & 3, rg = blockIdx.x >> 2;
    const int qbase = q * GP_QCOLS;

    // stage hsT quarter: 10 rows x 256 float4, coalesced
    {
        const float4* src = (const float4*)(hsT_in + qbase);
        float4* dst = (float4*)sh;
        #pragma unroll
        for (int k = 0; k < DD; ++k)
            dst[k * 256 + tid] = src[k * (N_ATOMS / 4) + tid];
    }
    __syncthreads();

    const int r0 = rg * GP_ROWS_BLK + wave * GP_RPW;
    const float4* Ar[GP_RPW];
    #pragma unroll
    for (int r = 0; r < GP_RPW; ++r)
        Ar[r] = (const float4*)(A + (size_t)(r0 + r) * N_ATOMS + qbase);
    const float4* sh4 = (const float4*)sh;

    float acc[GP_RPW][DD];
    #pragma unroll
    for (int r = 0; r < GP_RPW; ++r)
        #pragma unroll
        for (int d = 0; d < DD; ++d) acc[r][d] = 0.f;

    // 1024 cols = 256 float4 / 64 lanes = 4 iterations, FULLY unrolled:
    // 16 independent A loads issued up front.
    #pragma unroll
    for (int it = 0; it < GP_QCOLS / 256; ++it) {
        const int cb = it * 64 + lane;
        float4 a[GP_RPW];
        #pragma unroll
        for (int r = 0; r < GP_RPW; ++r) a[r] = Ar[r][cb];
        #pragma unroll
        for (int d = 0; d < DD; ++d) {
            float4 h = sh4[d * 256 + cb];
            #pragma unroll
            for (int r = 0; r < GP_RPW; ++r) {
                acc[r][d] += a[r].x * h.x;
                acc[r][d] += a[r].y * h.y;
                acc[r][d] += a[r].z * h.z;
                acc[r][d] += a[r].w * h.w;
            }
        }
    }

    // xor-butterfly reduce across 64 lanes
    #pragma unroll
    for (int m = 32; m >= 1; m >>= 1) {
        #pragma unroll
        for (int r = 0; r < GP_RPW; ++r)
            #pragma unroll
            for (int d = 0; d < DD; ++d)
                acc[r][d] += __shfl_xor(acc[r][d], m, 64);
    }

    if (lane == 0) {
        #pragma unroll
        for (int r = 0; r < GP_RPW; ++r)
            #pragma unroll
            for (int d = 0; d < DD; ++d)
                part[((size_t)q * N_ATOMS + r0 + r) * DD + d] = acc[r][d];
    }
}

// ---------------------------------------------------------------------------
// K2b: gnn_combine — xs_out = xs_in + sum_q part[q]; optional next-layer
// hsT_out = relu(xs_out @ Wg^T + bg)^T; optional compound partials.
// grid 16 x 256 threads, one thread per atom.
// ---------------------------------------------------------------------------
__global__ __launch_bounds__(256) void gnn_combine(
    const float* __restrict__ xs_in,
    const float* __restrict__ part,
    float* __restrict__ xs_out,
    float* __restrict__ hsT_out,         // may be null
    const float* __restrict__ Wg,
    const float* __restrict__ bg,
    float* __restrict__ comp_part)       // may be null; [16][DD]
{
    const int tid = threadIdx.x, wave = tid >> 6, lane = tid & 63;
    const int n = blockIdx.x * 256 + tid;

    float x[DD];
    #pragma unroll
    for (int d = 0; d < DD; ++d) {
        float v = xs_in[n * DD + d];
        #pragma unroll
        for (int q = 0; q < 4; ++q)
            v += part[((size_t)q * N_ATOMS + n) * DD + d];
        x[d] = v;
        xs_out[n * DD + d] = v;
    }
    if (hsT_out) {
        #pragma unroll
        for (int d = 0; d < DD; ++d) {
            float v = bg[d];
            #pragma unroll
            for (int k = 0; k < DD; ++k) v += Wg[d * DD + k] * x[k];
            hsT_out[(size_t)d * N_ATOMS + n] = fmaxf(v, 0.f);
        }
    }
    if (comp_part) {
        #pragma unroll
        for (int m = 32; m >= 1; m >>= 1) {
            #pragma unroll
            for (int d = 0; d < DD; ++d) x[d] += __shfl_xor(x[d], m, 64);
        }
        __shared__ float s[4][DD];
        if (lane == 0) {
            #pragma unroll
            for (int d = 0; d < DD; ++d) s[wave][d] = x[d];
        }
        __syncthreads();
        if (tid < DD)
            comp_part[blockIdx.x * DD + tid] =
                s[0][tid] + s[1][tid] + s[2][tid] + s[3][tid];
    }
}

// ---------------------------------------------------------------------------
// K3: reduce compound partials [16][10] -> comp[10] (mean over atoms)
// ---------------------------------------------------------------------------
__global__ __launch_bounds__(256) void reduce_comp(
    const float* __restrict__ part, int npart, float* __restrict__ comp)
{
    const int tid = threadIdx.x, wave = tid >> 6, lane = tid & 63;
    float v[DD];
    #pragma unroll
    for (int d = 0; d < DD; ++d) v[d] = 0.f;
    for (int p = tid; p < npart; p += 256) {
        #pragma unroll
        for (int d = 0; d < DD; ++d) v[d] += part[p * DD + d];
    }
    #pragma unroll
    for (int off = 32; off >= 1; off >>= 1) {
        #pragma unroll
        for (int d = 0; d < DD; ++d) v[d] += __shfl_down(v[d], off, 64);
    }
    __shared__ float s[4][DD];
    if (lane == 0) {
        #pragma unroll
        for (int d = 0; d < DD; ++d) s[wave][d] = v[d];
    }
    __syncthreads();
    if (tid < DD)
        comp[tid] = (s[0][tid] + s[1][tid] + s[2][tid] + s[3][tid]) * (1.f / N_ATOMS);
}

// ---------------------------------------------------------------------------
// K4: one CNN layer over [L_WORDS, 10], 23x23 kernel, pad 11.
//   out[l,d] = relu(b + sum_i sum_c in[l+i-11, c] * w[i, c-d+11])
// Layer 0 fuses the word-embedding gather into the LDS staging.
// ---------------------------------------------------------------------------
#define CONV_BLOCK 256

__global__ __launch_bounds__(CONV_BLOCK) void conv_layer(
    const float* __restrict__ tin,        // null => gather from embedding
    const int* __restrict__ words,
    const float* __restrict__ embed_word,
    const float* __restrict__ w,          // [23*23]
    const float* __restrict__ bptr,       // scalar bias
    float* __restrict__ tout)
{
    __shared__ float s[(CONV_BLOCK + 2 * HALO) * 11];
    const int tid = threadIdx.x;
    const int l0 = blockIdx.x * CONV_BLOCK;

    for (int idx = tid; idx < (CONV_BLOCK + 2 * HALO) * DD; idx += CONV_BLOCK) {
        int rr = idx / DD, d = idx - rr * DD;
        int gr = l0 - HALO + rr;
        float v = 0.f;
        if (gr >= 0 && gr < L_WORDS) {
            if (tin) v = tin[(size_t)gr * DD + d];
            else     v = embed_word[(size_t)words[gr] * DD + d];
        }
        s[rr * 11 + d] = v;
    }
    __syncthreads();

    const float bias = *bptr;
    float acc[DD];
    #pragma unroll
    for (int d = 0; d < DD; ++d) acc[d] = bias;

    for (int i = 0; i < 23; ++i) {
        float row[DD];
        const float* sr = &s[(tid + i) * 11];
        #pragma unroll
        for (int c = 0; c < DD; ++c) row[c] = sr[c];
        #pragma unroll
        for (int d = 0; d < DD; ++d) {
            #pragma unroll
            for (int c = 0; c < DD; ++c)
                acc[d] += row[c] * w[i * 23 + (c - d + 11)];
        }
    }
    const int l = l0 + tid;
    #pragma unroll
    for (int d = 0; d < DD; ++d)
        tout[(size_t)l * DD + d] = fmaxf(acc[d], 0.f);
}

// ---------------------------------------------------------------------------
// K5: attention pooling -> per-block partial sums of wgt*hp  [64][10]
// ---------------------------------------------------------------------------
__global__ __launch_bounds__(1024) void attention_pool(
    const float* __restrict__ xs_p,
    const float* __restrict__ comp,            // [10], already meaned
    const float* __restrict__ Wa, const float* __restrict__ ba,
    float* __restrict__ att_part)              // [gridDim.x][DD]
{
    const int tid = threadIdx.x, wave = tid >> 6, lane = tid & 63;
    const int l = blockIdx.x * 1024 + tid;

    float h[DD];
    #pragma unroll
    for (int d = 0; d < DD; ++d) {
        float v = ba[d];
        #pragma unroll
        for (int k = 0; k < DD; ++k) v += Wa[d * DD + k] * comp[k];
        h[d] = fmaxf(v, 0.f);
    }

    float row[DD];
    #pragma unroll
    for (int d = 0; d < DD; ++d) row[d] = xs_p[(size_t)l * DD + d];

    float hp[DD], dotv = 0.f;
    #pragma unroll
    for (int d = 0; d < DD; ++d) {
        float v = ba[d];
        #pragma unroll
        for (int k = 0; k < DD; ++k) v += Wa[d * DD + k] * row[k];
        hp[d] = fmaxf(v, 0.f);
        dotv += h[d] * hp[d];
    }
    const float wgt = tanhf(dotv);

    float y[DD];
    #pragma unroll
    for (int d = 0; d < DD; ++d) y[d] = wgt * hp[d];

    #pragma unroll
    for (int off = 32; off >= 1; off >>= 1) {
        #pragma unroll
        for (int d = 0; d < DD; ++d) y[d] += __shfl_down(y[d], off, 64);
    }
    __shared__ float s[16][DD];
    if (lane == 0) {
        #pragma unroll
        for (int d = 0; d < DD; ++d) s[wave][d] = y[d];
    }
    __syncthreads();
    if (tid < DD) {
        float v = 0.f;
        #pragma unroll
        for (int wv = 0; wv < 16; ++wv) v += s[wv][tid];
        att_part[blockIdx.x * DD + tid] = v;
    }
}

// ---------------------------------------------------------------------------
// K6: reduce att partials [64][10] -> protein mean; fusion MLP -> out[2]
// ---------------------------------------------------------------------------
__global__ __launch_bounds__(64) void final_mlp(
    const float* __restrict__ comp,            // [10] meaned
    const float* __restrict__ att_part,        // [64][10]
    const float* __restrict__ Wo, const float* __restrict__ bo,
    const float* __restrict__ Wi, const float* __restrict__ bi,
    float* __restrict__ out)
{
    const int t = threadIdx.x;
    float a[DD];
    #pragma unroll
    for (int d = 0; d < DD; ++d) a[d] = att_part[t * DD + d];
    #pragma unroll
    for (int off = 32; off >= 1; off >>= 1) {
        #pragma unroll
        for (int d = 0; d < DD; ++d) a[d] += __shfl_down(a[d], off, 64);
    }

    __shared__ float cat[20];
    if (t < DD) cat[t] = comp[t];
    if (t == 0) {
        #pragma unroll
        for (int d = 0; d < DD; ++d) cat[DD + d] = a[d] * (1.f / L_WORDS);
    }
    __syncthreads();

    for (int j = 0; j < 3; ++j) {
        float v = 0.f;
        if (t < 20) {
            v = bo[j * 20 + t];
            for (int k = 0; k < 20; ++k) v += Wo[j * 400 + t * 20 + k] * cat[k];
        }
        __syncthreads();
        if (t < 20) cat[t] = fmaxf(v, 0.f);
        __syncthreads();
    }
    if (t < 2) {
        float v = bi[t];
        for (int k = 0; k < 20; ++k) v += Wi[t * 20 + k] * cat[k];
        out[t] = v;
    }
}

// ---------------------------------------------------------------------------
extern "C" void kernel_launch(void* const* d_in, const int* in_sizes, int n_in,
                              void* d_out, int out_size, void* d_ws, size_t ws_size,
                              hipStream_t stream)
{
    const int*   fp     = (const int*)d_in[0];
    const float* A      = (const float*)d_in[1];
    const int*   words  = (const int*)d_in[2];
    const float* emb_fp = (const float*)d_in[3];
    const float* emb_w  = (const float*)d_in[4];
    const float* Wg     = (const float*)d_in[5];   // [3][10][10]
    const float* bg     = (const float*)d_in[6];   // [3][10]
    const float* Wc     = (const float*)d_in[7];   // [3][529]
    const float* bc     = (const float*)d_in[8];   // [3]
    const float* Wa     = (const float*)d_in[9];   // [10][10]
    const float* ba     = (const float*)d_in[10];  // [10]
    const float* Wo     = (const float*)d_in[11];  // [3][20][20]
    const float* bo     = (const float*)d_in[12];  // [3][20]
    const float* Wi     = (const float*)d_in[13];  // [2][20]
    const float* bi     = (const float*)d_in[14];  // [2]
    float* out = (float*)d_out;
    float* ws  = (float*)d_ws;

    float* xs0  = ws;                          // 40960
    float* xs1  = ws + 40960;                  // 40960
    float* hsT0 = ws + 81920;                  // 40960 (10 x 4096)
    float* hsT1 = ws + 122880;                 // 40960
    float* t0   = ws + 163840;                 // 655360
    float* t1   = ws + 163840 + 655360;        // 655360
    float* comp = ws + 163840 + 2 * 655360;    // 16
    float* part = comp + 16;                   // 4*4096*10 = 163840
    float* comp_part = part + 163840;          // 16*10
    float* att_part  = comp_part + 256;        // 64*10

    const int gp_grid = (N_ATOMS / GP_ROWS_BLK) * 4;   // 1024

    // ---- GNN ----
    gnn_embed<<<N_ATOMS / 256, 256, 0, stream>>>(fp, emb_fp, Wg, bg, xs0, hsT0);
    gnn_partial<<<gp_grid, GP_BLOCK, 0, stream>>>(A, hsT0, part);
    gnn_combine<<<N_ATOMS / 256, 256, 0, stream>>>(
        xs0, part, xs1, hsT1, Wg + 100, bg + 10, nullptr);
    gnn_partial<<<gp_grid, GP_BLOCK, 0, stream>>>(A, hsT1, part);
    gnn_combine<<<N_ATOMS / 256, 256, 0, stream>>>(
        xs1, part, xs0, hsT0, Wg + 200, bg + 20, nullptr);
    gnn_partial<<<gp_grid, GP_BLOCK, 0, stream>>>(A, hsT0, part);
    gnn_combine<<<N_ATOMS / 256, 256, 0, stream>>>(
        xs0, part, xs1, nullptr, nullptr, nullptr, comp_part);
    reduce_comp<<<1, 256, 0, stream>>>(comp_part, 16, comp);

    // ---- CNN ---- (layer0 fuses embedding gather)
    conv_layer<<<L_WORDS / CONV_BLOCK, CONV_BLOCK, 0, stream>>>(
        nullptr, words, emb_w, Wc, bc, t0);
    conv_layer<<<L_WORDS / CONV_BLOCK, CONV_BLOCK, 0, stream>>>(
        t0, nullptr, nullptr, Wc + 529, bc + 1, t1);
    conv_layer<<<L_WORDS / CONV_BLOCK, CONV_BLOCK, 0, stream>>>(
        t1, nullptr, nullptr, Wc + 1058, bc + 2, t0);

    // ---- attention + fusion ----
    attention_pool<<<L_WORDS / 1024, 1024, 0, stream>>>(t0, comp, Wa, ba, att_part);
    final_mlp<<<1, 64, 0, stream>>>(comp, att_part, Wo, bo, Wi, bi, out);
}

// Round 5
// 233.587 us; speedup vs baseline: 3.3316x; 1.1269x over previous
//
#include <hip/hip_runtime.h>
#include <hip/hip_bf16.h>
#include <math.h>

#define N_ATOMS 4096
#define L_WORDS 65536
#define DD 10
#define HALO 11

// ---------------------------------------------------------------------------
// K1: fingerprint embedding gather; xs0 row-major, hs0 TRANSPOSED [d][n]
// ---------------------------------------------------------------------------
__global__ __launch_bounds__(256) void gnn_embed(
    const int* __restrict__ fp, const float* __restrict__ embed_fp,
    const float* __restrict__ Wg0, const float* __restrict__ bg0,
    float* __restrict__ xs0, float* __restrict__ hsT0)
{
    int n = blockIdx.x * blockDim.x + threadIdx.x;
    if (n >= N_ATOMS) return;
    float x[DD];
    const float* e = embed_fp + (size_t)fp[n] * DD;
    #pragma unroll
    for (int d = 0; d < DD; ++d) { x[d] = e[d]; xs0[n * DD + d] = x[d]; }
    #pragma unroll
    for (int d = 0; d < DD; ++d) {
        float v = bg0[d];
        #pragma unroll
        for (int k = 0; k < DD; ++k) v += Wg0[d * DD + k] * x[k];
        hsT0[d * N_ATOMS + n] = fmaxf(v, 0.f);   // coalesced per d
    }
}

// ---------------------------------------------------------------------------
// K2: fused_layer — role-split grid.
//   blocks [0,256):   CNN layer (VALU-bound, 1 word/thread)
//   blocks [256,1280): GNN partial A@hs over a column quarter (memory-bound)
// The two roles are independent within a layer; co-scheduling hides the
// conv's VALU time under the gnn's memory waits. Union 40-KB LDS so any
// 4 blocks pack per CU (160 KB).
// GNN role: block = 4 waves, 16 rows (4/wave), 1024 cols staged in LDS;
// hot loop's vmem queue carries ONLY the A stream (16 dwordx4 in flight,
// fully unrolled); h via ds_read_b128, conflict-free.
// ---------------------------------------------------------------------------
#define GP_BLOCK 256
#define GP_RPW 4
#define GP_ROWS_BLK 16
#define GP_QCOLS 1024
#define CONV_BLOCKS 256
#define CONV_BLOCK 256

__global__ __launch_bounds__(256, 4) void fused_layer(
    // gnn role:
    const float* __restrict__ A,
    const float* __restrict__ hsT_in,
    float* __restrict__ part,            // [4][N_ATOMS][DD]
    // conv role:
    const float* __restrict__ tin,       // null => gather from embedding
    const int* __restrict__ words,
    const float* __restrict__ embed_word,
    const float* __restrict__ w,         // [23*23]
    const float* __restrict__ bptr,      // scalar bias
    float* __restrict__ tout)
{
    __shared__ float sh[DD * GP_QCOLS];  // 40 KB, union for both roles
    const int tid = threadIdx.x;

    if (blockIdx.x < CONV_BLOCKS) {
        // ================= CONV ROLE =================
        // out[l,d] = relu(b + sum_i sum_c in[l+i-11,c] * w[i, c-d+11])
        float* s = sh;                   // uses (256+22)*11 = 3058 floats
        const int l0 = blockIdx.x * CONV_BLOCK;

        for (int idx = tid; idx < (CONV_BLOCK + 2 * HALO) * DD; idx += CONV_BLOCK) {
            int rr = idx / DD, d = idx - rr * DD;
            int gr = l0 - HALO + rr;
            float v = 0.f;
            if (gr >= 0 && gr < L_WORDS) {
                if (tin) v = tin[(size_t)gr * DD + d];
                else     v = embed_word[(size_t)words[gr] * DD + d];
            }
            s[rr * 11 + d] = v;          // stride 11: 2 lanes/bank = free
        }
        __syncthreads();

        const float bias = *bptr;
        float acc[DD];
        #pragma unroll
        for (int d = 0; d < DD; ++d) acc[d] = bias;

        for (int i = 0; i < 23; ++i) {
            float row[DD];
            const float* sr = &s[(tid + i) * 11];
            #pragma unroll
            for (int c = 0; c < DD; ++c) row[c] = sr[c];
            #pragma unroll
            for (int d = 0; d < DD; ++d) {
                #pragma unroll
                for (int c = 0; c < DD; ++c)
                    acc[d] += row[c] * w[i * 23 + (c - d + 11)];
            }
        }
        const int l = l0 + tid;
        #pragma unroll
        for (int d = 0; d < DD; ++d)
            tout[(size_t)l * DD + d] = fmaxf(acc[d], 0.f);
    } else {
        // ================= GNN ROLE =================
        const int b = blockIdx.x - CONV_BLOCKS;
        const int wave = tid >> 6, lane = tid & 63;
        const int q = b & 3, rg = b >> 2;
        const int qbase = q * GP_QCOLS;

        // stage hsT quarter: 10 rows x 256 float4, coalesced
        {
            const float4* src = (const float4*)(hsT_in + qbase);
            float4* dst = (float4*)sh;
            #pragma unroll
            for (int k = 0; k < DD; ++k)
                dst[k * 256 + tid] = src[k * (N_ATOMS / 4) + tid];
        }
        __syncthreads();

        const int r0 = rg * GP_ROWS_BLK + wave * GP_RPW;
        const float4* Ar[GP_RPW];
        #pragma unroll
        for (int r = 0; r < GP_RPW; ++r)
            Ar[r] = (const float4*)(A + (size_t)(r0 + r) * N_ATOMS + qbase);
        const float4* sh4 = (const float4*)sh;

        float acc[GP_RPW][DD];
        #pragma unroll
        for (int r = 0; r < GP_RPW; ++r)
            #pragma unroll
            for (int d = 0; d < DD; ++d) acc[r][d] = 0.f;

        // 4 iterations fully unrolled: 16 independent A loads in flight
        #pragma unroll
        for (int it = 0; it < GP_QCOLS / 256; ++it) {
            const int cb = it * 64 + lane;
            float4 a[GP_RPW];
            #pragma unroll
            for (int r = 0; r < GP_RPW; ++r) a[r] = Ar[r][cb];
            #pragma unroll
            for (int d = 0; d < DD; ++d) {
                float4 h = sh4[d * 256 + cb];
                #pragma unroll
                for (int r = 0; r < GP_RPW; ++r) {
                    acc[r][d] += a[r].x * h.x;
                    acc[r][d] += a[r].y * h.y;
                    acc[r][d] += a[r].z * h.z;
                    acc[r][d] += a[r].w * h.w;
                }
            }
        }

        // xor-butterfly reduce across 64 lanes
        #pragma unroll
        for (int m = 32; m >= 1; m >>= 1) {
            #pragma unroll
            for (int r = 0; r < GP_RPW; ++r)
                #pragma unroll
                for (int d = 0; d < DD; ++d)
                    acc[r][d] += __shfl_xor(acc[r][d], m, 64);
        }

        if (lane == 0) {
            #pragma unroll
            for (int r = 0; r < GP_RPW; ++r)
                #pragma unroll
                for (int d = 0; d < DD; ++d)
                    part[((size_t)q * N_ATOMS + r0 + r) * DD + d] = acc[r][d];
        }
    }
}

// ---------------------------------------------------------------------------
// K2b: gnn_combine — xs_out = xs_in + sum_q part[q]; optional next-layer
// hsT_out = relu(xs_out @ Wg^T + bg)^T; optional compound partials.
// ---------------------------------------------------------------------------
__global__ __launch_bounds__(256) void gnn_combine(
    const float* __restrict__ xs_in,
    const float* __restrict__ part,
    float* __restrict__ xs_out,
    float* __restrict__ hsT_out,         // may be null
    const float* __restrict__ Wg,
    const float* __restrict__ bg,
    float* __restrict__ comp_part)       // may be null; [16][DD]
{
    const int tid = threadIdx.x, wave = tid >> 6, lane = tid & 63;
    const int n = blockIdx.x * 256 + tid;

    float x[DD];
    #pragma unroll
    for (int d = 0; d < DD; ++d) {
        float v = xs_in[n * DD + d];
        #pragma unroll
        for (int q = 0; q < 4; ++q)
            v += part[((size_t)q * N_ATOMS + n) * DD + d];
        x[d] = v;
        xs_out[n * DD + d] = v;
    }
    if (hsT_out) {
        #pragma unroll
        for (int d = 0; d < DD; ++d) {
            float v = bg[d];
            #pragma unroll
            for (int k = 0; k < DD; ++k) v += Wg[d * DD + k] * x[k];
            hsT_out[(size_t)d * N_ATOMS + n] = fmaxf(v, 0.f);
        }
    }
    if (comp_part) {
        #pragma unroll
        for (int m = 32; m >= 1; m >>= 1) {
            #pragma unroll
            for (int d = 0; d < DD; ++d) x[d] += __shfl_xor(x[d], m, 64);
        }
        __shared__ float s[4][DD];
        if (lane == 0) {
            #pragma unroll
            for (int d = 0; d < DD; ++d) s[wave][d] = x[d];
        }
        __syncthreads();
        if (tid < DD)
            comp_part[blockIdx.x * DD + tid] =
                s[0][tid] + s[1][tid] + s[2][tid] + s[3][tid];
    }
}

// ---------------------------------------------------------------------------
// K3: reduce compound partials [16][10] -> comp[10] (mean over atoms)
// ---------------------------------------------------------------------------
__global__ __launch_bounds__(256) void reduce_comp(
    const float* __restrict__ part, int npart, float* __restrict__ comp)
{
    const int tid = threadIdx.x, wave = tid >> 6, lane = tid & 63;
    float v[DD];
    #pragma unroll
    for (int d = 0; d < DD; ++d) v[d] = 0.f;
    for (int p = tid; p < npart; p += 256) {
        #pragma unroll
        for (int d = 0; d < DD; ++d) v[d] += part[p * DD + d];
    }
    #pragma unroll
    for (int off = 32; off >= 1; off >>= 1) {
        #pragma unroll
        for (int d = 0; d < DD; ++d) v[d] += __shfl_down(v[d], off, 64);
    }
    __shared__ float s[4][DD];
    if (lane == 0) {
        #pragma unroll
        for (int d = 0; d < DD; ++d) s[wave][d] = v[d];
    }
    __syncthreads();
    if (tid < DD)
        comp[tid] = (s[0][tid] + s[1][tid] + s[2][tid] + s[3][tid]) * (1.f / N_ATOMS);
}

// ---------------------------------------------------------------------------
// K5: attention pooling -> per-block partial sums of wgt*hp  [64][10]
// ---------------------------------------------------------------------------
__global__ __launch_bounds__(1024) void attention_pool(
    const float* __restrict__ xs_p,
    const float* __restrict__ comp,            // [10], already meaned
    const float* __restrict__ Wa, const float* __restrict__ ba,
    float* __restrict__ att_part)              // [gridDim.x][DD]
{
    const int tid = threadIdx.x, wave = tid >> 6, lane = tid & 63;
    const int l = blockIdx.x * 1024 + tid;

    float h[DD];
    #pragma unroll
    for (int d = 0; d < DD; ++d) {
        float v = ba[d];
        #pragma unroll
        for (int k = 0; k < DD; ++k) v += Wa[d * DD + k] * comp[k];
        h[d] = fmaxf(v, 0.f);
    }

    float row[DD];
    #pragma unroll
    for (int d = 0; d < DD; ++d) row[d] = xs_p[(size_t)l * DD + d];

    float hp[DD], dotv = 0.f;
    #pragma unroll
    for (int d = 0; d < DD; ++d) {
        float v = ba[d];
        #pragma unroll
        for (int k = 0; k < DD; ++k) v += Wa[d * DD + k] * row[k];
        hp[d] = fmaxf(v, 0.f);
        dotv += h[d] * hp[d];
    }
    const float wgt = tanhf(dotv);

    float y[DD];
    #pragma unroll
    for (int d = 0; d < DD; ++d) y[d] = wgt * hp[d];

    #pragma unroll
    for (int off = 32; off >= 1; off >>= 1) {
        #pragma unroll
        for (int d = 0; d < DD; ++d) y[d] += __shfl_down(y[d], off, 64);
    }
    __shared__ float s[16][DD];
    if (lane == 0) {
        #pragma unroll
        for (int d = 0; d < DD; ++d) s[wave][d] = y[d];
    }
    __syncthreads();
    if (tid < DD) {
        float v = 0.f;
        #pragma unroll
        for (int wv = 0; wv < 16; ++wv) v += s[wv][tid];
        att_part[blockIdx.x * DD + tid] = v;
    }
}

// ---------------------------------------------------------------------------
// K6: reduce att partials [64][10] -> protein mean; fusion MLP -> out[2]
// ---------------------------------------------------------------------------
__global__ __launch_bounds__(64) void final_mlp(
    const float* __restrict__ comp,            // [10] meaned
    const float* __restrict__ att_part,        // [64][10]
    const float* __restrict__ Wo, const float* __restrict__ bo,
    const float* __restrict__ Wi, const float* __restrict__ bi,
    float* __restrict__ out)
{
    const int t = threadIdx.x;
    float a[DD];
    #pragma unroll
    for (int d = 0; d < DD; ++d) a[d] = att_part[t * DD + d];
    #pragma unroll
    for (int off = 32; off >= 1; off >>= 1) {
        #pragma unroll
        for (int d = 0; d < DD; ++d) a[d] += __shfl_down(a[d], off, 64);
    }

    __shared__ float cat[20];
    if (t < DD) cat[t] = comp[t];
    if (t == 0) {
        #pragma unroll
        for (int d = 0; d < DD; ++d) cat[DD + d] = a[d] * (1.f / L_WORDS);
    }
    __syncthreads();

    for (int j = 0; j < 3; ++j) {
        float v = 0.f;
        if (t < 20) {
            v = bo[j * 20 + t];
            for (int k = 0; k < 20; ++k) v += Wo[j * 400 + t * 20 + k] * cat[k];
        }
        __syncthreads();
        if (t < 20) cat[t] = fmaxf(v, 0.f);
        __syncthreads();
    }
    if (t < 2) {
        float v = bi[t];
        for (int k = 0; k < 20; ++k) v += Wi[t * 20 + k] * cat[k];
        out[t] = v;
    }
}

// ---------------------------------------------------------------------------
extern "C" void kernel_launch(void* const* d_in, const int* in_sizes, int n_in,
                              void* d_out, int out_size, void* d_ws, size_t ws_size,
                              hipStream_t stream)
{
    const int*   fp     = (const int*)d_in[0];
    const float* A      = (const float*)d_in[1];
    const int*   words  = (const int*)d_in[2];
    const float* emb_fp = (const float*)d_in[3];
    const float* emb_w  = (const float*)d_in[4];
    const float* Wg     = (const float*)d_in[5];   // [3][10][10]
    const float* bg     = (const float*)d_in[6];   // [3][10]
    const float* Wc     = (const float*)d_in[7];   // [3][529]
    const float* bc     = (const float*)d_in[8];   // [3]
    const float* Wa     = (const float*)d_in[9];   // [10][10]
    const float* ba     = (const float*)d_in[10];  // [10]
    const float* Wo     = (const float*)d_in[11];  // [3][20][20]
    const float* bo     = (const float*)d_in[12];  // [3][20]
    const float* Wi     = (const float*)d_in[13];  // [2][20]
    const float* bi     = (const float*)d_in[14];  // [2]
    float* out = (float*)d_out;
    float* ws  = (float*)d_ws;

    float* xs0  = ws;                          // 40960
    float* xs1  = ws + 40960;                  // 40960
    float* hsT0 = ws + 81920;                  // 40960 (10 x 4096)
    float* hsT1 = ws + 122880;                 // 40960
    float* t0   = ws + 163840;                 // 655360
    float* t1   = ws + 163840 + 655360;        // 655360
    float* comp = ws + 163840 + 2 * 655360;    // 16
    float* part = comp + 16;                   // 4*4096*10 = 163840
    float* comp_part = part + 163840;          // 16*10
    float* att_part  = comp_part + 256;        // 64*10

    const int fused_grid = CONV_BLOCKS + (N_ATOMS / GP_ROWS_BLK) * 4;  // 1280

    // ---- GNN layer i runs fused with CNN layer i (independent work) ----
    gnn_embed<<<N_ATOMS / 256, 256, 0, stream>>>(fp, emb_fp, Wg, bg, xs0, hsT0);

    fused_layer<<<fused_grid, 256, 0, stream>>>(
        A, hsT0, part, nullptr, words, emb_w, Wc, bc, t0);
    gnn_combine<<<N_ATOMS / 256, 256, 0, stream>>>(
        xs0, part, xs1, hsT1, Wg + 100, bg + 10, nullptr);

    fused_layer<<<fused_grid, 256, 0, stream>>>(
        A, hsT1, part, t0, nullptr, nullptr, Wc + 529, bc + 1, t1);
    gnn_combine<<<N_ATOMS / 256, 256, 0, stream>>>(
        xs1, part, xs0, hsT0, Wg + 200, bg + 20, nullptr);

    fused_layer<<<fused_grid, 256, 0, stream>>>(
        A, hsT0, part, t1, nullptr, nullptr, Wc + 1058, bc + 2, t0);
    gnn_combine<<<N_ATOMS / 256, 256, 0, stream>>>(
        xs0, part, xs1, nullptr, nullptr, nullptr, comp_part);
    reduce_comp<<<1, 256, 0, stream>>>(comp_part, 16, comp);

    // ---- attention + fusion ----
    attention_pool<<<L_WORDS / 1024, 1024, 0, stream>>>(t0, comp, Wa, ba, att_part);
    final_mlp<<<1, 64, 0, stream>>>(comp, att_part, Wo, bo, Wi, bi, out);
}